// Round 3
// baseline (235.351 us; speedup 1.0000x reference)
//
#include <hip/hip_runtime.h>
#include <float.h>

#define H 64
#define W 512
#define SPLIT 8   // blocks per (tensor,h): 2*64*8 = 1024 blocks = 4 blocks/CU

// ---------------------------------------------------------------------------
// Fused masked-exp-norm row statistics for BOTH cost volumes in one dispatch.
// Quarter-wave layout: each 16-lane group owns one row (4 rows/wave), each
// lane holds 32 elements (j = seg*64 + (lane&15)*4 + k, seg<8, k<4).
// Cross-lane reductions are 4-round xor butterflies within the group; one
// butterfly instruction reduces 4 rows simultaneously (ILP hides DS latency).
// Per row i of a [H,W,W] cost volume, without materializing att:
//   disp_ini[i] = i - sum_j att[i,j]*j
//   colsum[j]  += sum_i att[i,j]          (-> valid mask, thresholded later)
//   raw[i]      = 3-tap subpixel around argmax (gen_raw_disp fused)
// lower=true  (cost2 -> att_r2l): tril mask (j<=i), pos = (i-j)*pscale
// lower=false (cost1 -> att_l2r): triu mask (j>=i), pos = (j-i)*pscale
// Argmax fused into max-reduction (exp monotone; first occurrence kept).
// ---------------------------------------------------------------------------
__global__ __launch_bounds__(512) void attn_stats_all(
    const float* __restrict__ cost1, const float* __restrict__ cost2,
    float* __restrict__ disp_r2l, float* __restrict__ disp_l2r,
    float* __restrict__ cs_r2l,  float* __restrict__ cs_l2r,
    float* __restrict__ out)
{
  __shared__ float scol[4 * 513];        // per-group slices, 513-stride: 2-way banks only
  const int tid  = threadIdx.x;
  const int lane = tid & 63;
  const int wid  = tid >> 6;             // 0..7
  const int g    = lane >> 4;            // group 0..3 within wave
  const int sub  = lane & 15;            // lane within group
  const int sub4 = sub * 4;
  const int gid  = blockIdx.x;
  const bool lower = (gid & 1) == 0;     // interleave tensors across CUs/XCDs
  const int rest = gid >> 1;
  const int h    = rest / SPLIT;
  const int s    = rest % SPLIT;

  const float* cost = lower ? cost2 : cost1;
  float* disp = lower ? disp_r2l : disp_l2r;
  float* csum = lower ? cs_r2l  : cs_l2r;
  float* raw  = out + (lower ? 2 : 3) * (H * W);

  for (int t = tid; t < 4 * 513; t += 512) scol[t] = 0.f;
  __syncthreads();

  float cacc[32];
  #pragma unroll
  for (int q = 0; q < 32; q++) cacc[q] = 0.f;

  const float pscale = 2.0f / 511.0f;    // linspace(0,2,512) step
  const float* hb = cost + (size_t)h * W * W;

  for (int t = 0; t < 2; t++) {          // 64 rows/block, 32 rows/iter
    const int i = s * 64 + t * 32 + wid * 4 + g;
    const float* rp = hb + (size_t)i * W;

    float c[32];
    #pragma unroll
    for (int seg = 0; seg < 8; seg++) {
      const float4 v = ((const float4*)rp)[seg * 16 + sub];
      c[seg * 4 + 0] = v.x; c[seg * 4 + 1] = v.y;
      c[seg * 4 + 2] = v.z; c[seg * 4 + 3] = v.w;
    }

    // ---- fused max + argmax over valid entries (first occurrence on ties)
    float mxv = -FLT_MAX;
    int   bj  = W;
    #pragma unroll
    for (int seg = 0; seg < 8; seg++) {
      #pragma unroll
      for (int k = 0; k < 4; k++) {
        const int j = seg * 64 + sub4 + k;     // ascending in (seg,k)
        const bool vld = lower ? (j <= i) : (j >= i);
        if (vld && c[seg * 4 + k] > mxv) { mxv = c[seg * 4 + k]; bj = j; }
      }
    }
    #pragma unroll
    for (int off = 8; off; off >>= 1) {        // 4-round group butterfly
      const float ov = __shfl_xor(mxv, off);
      const int   oj = __shfl_xor(bj, off);
      if (ov > mxv || (ov == mxv && oj < bj)) { mxv = ov; bj = oj; }
    }
    const int hi = bj;                         // group-uniform argmax
    float mx = mxv;
    // tril/triu zeros participate in the exp-max whenever the row has any
    if (lower ? (i < W - 1) : (i > 0)) mx = fmaxf(mx, 0.f);

    // ---- exp + row sums + 3-tap partials (c[] overwritten with e)
    float ssum = 0.f, wsum = 0.f, s0 = 0.f, s1 = 0.f;
    #pragma unroll
    for (int seg = 0; seg < 8; seg++) {
      #pragma unroll
      for (int k = 0; k < 4; k++) {
        const int j = seg * 64 + sub4 + k;
        const bool vld = lower ? (j <= i) : (j >= i);
        const float e = vld ? __expf(c[seg * 4 + k] - mx) : 0.f;
        c[seg * 4 + k] = e;
        ssum += e;
        wsum += e * (float)j;
        if (j >= hi - 1 && j <= hi + 1) {
          const float pr = fmaxf((float)(lower ? (i - j) : (j - i)) * pscale, 0.f);
          s0 += e;
          s1 += e * pr;
        }
      }
    }
    #pragma unroll
    for (int off = 8; off; off >>= 1) {
      ssum += __shfl_xor(ssum, off);
      wsum += __shfl_xor(wsum, off);
    }
    const float inv = 1.0f / (ssum + 1e-8f);

    // ---- gather 3-tap partials: taps live in <=2 known lanes of the group
    const int jlo = hi > 0 ? hi - 1 : 0;
    const int jh2 = hi < W - 1 ? hi + 1 : W - 1;
    const int l1 = (lane & 48) | ((jlo >> 2) & 15);
    const int l2 = (lane & 48) | ((jh2 >> 2) & 15);
    float t0 = __shfl(s0, l1), t1 = __shfl(s1, l1);
    if (l2 != l1) { t0 += __shfl(s0, l2); t1 += __shfl(s1, l2); }

    #pragma unroll
    for (int q = 0; q < 32; q++) cacc[q] += c[q] * inv;

    if (sub == 0) {
      disp[h * W + i] = (float)i - wsum * inv;
      const float n0 = t0 * inv;               // sum of the 3 att taps
      raw[h * W + i]  = (t1 * inv) / (n0 < 0.1f ? 1.0f : n0);
    }
  }

  // column-sum reduction: regs -> per-group LDS slice -> global
  float* sc = scol + g * 513;
  #pragma unroll
  for (int seg = 0; seg < 8; seg++) {
    #pragma unroll
    for (int k = 0; k < 4; k++)
      atomicAdd(&sc[seg * 64 + sub4 + k], cacc[seg * 4 + k]);
  }
  __syncthreads();
  const float v = scol[tid] + scol[513 + tid] + scol[2 * 513 + tid] + scol[3 * 513 + tid];
  atomicAdd(&csum[h * W + tid], v);
}

// ---------------------------------------------------------------------------
// Closed-form hole fill (the W-step scan converges to this):
//   valid i            -> disp_ini[i]
//   invalid, valid p<i -> disp_ini[p] * (1+1e-4)^-(i-p)   (left-to-right pass)
//   invalid prefix     -> disp_ini[p0] * (1+1e-4)^-(p0-i) (right-to-left pass)
//   no valid in row    -> 0
// One wave per (pair, h) row.
// ---------------------------------------------------------------------------
__global__ __launch_bounds__(64) void fill_rows(
    const float* __restrict__ dispA, const float* __restrict__ csA,
    const float* __restrict__ dispB, const float* __restrict__ csB,
    float* __restrict__ out)
{
  __shared__ float xrow[W];
  const int pair = blockIdx.x >> 6;   // 0: ch0 (r2l disp, vm_left), 1: ch1
  const int h    = blockIdx.x & 63;
  const float* dsp = (pair ? dispB : dispA) + h * W;
  const float* cs  = (pair ? csB  : csA ) + h * W;
  float* o = out + pair * (H * W) + h * W;
  const int lane = threadIdx.x;
  const int j0 = lane * 8;

  float x[8];
  bool m[8];
  int incl[8];
  int run = -1, fv = W;
  #pragma unroll
  for (int k = 0; k < 8; k++) {
    x[k] = dsp[j0 + k];
    m[k] = cs[j0 + k] > 0.1f;
    xrow[j0 + k] = x[k];
    if (m[k]) { run = j0 + k; if (fv == W) fv = j0 + k; }
    incl[k] = run;
  }
  // inclusive max-scan across lanes of "last valid index in my segment"
  int v = run;
  #pragma unroll
  for (int off = 1; off < 64; off <<= 1) {
    const int tv = __shfl_up(v, off);
    if (lane >= off) v = max(v, tv);
  }
  int excl = __shfl_up(v, 1);
  if (lane == 0) excl = -1;
  // first valid index in the whole row
  int p0 = fv;
  #pragma unroll
  for (int off = 32; off; off >>= 1) p0 = min(p0, __shfl_xor(p0, off));
  __syncthreads();

  const float C2 = -1.4426229e-4f;  // -log2(1 + 1e-4)
  #pragma unroll
  for (int k = 0; k < 8; k++) {
    const int jj = j0 + k;
    float ov;
    if (m[k]) {
      ov = x[k];
    } else {
      const int p = max(excl, incl[k]);
      if (p >= 0)        ov = xrow[p]  * exp2f(C2 * (float)(jj - p));
      else if (p0 < W)   ov = xrow[p0] * exp2f(C2 * (float)(p0 - jj));
      else               ov = 0.f;
    }
    o[jj] = ov;
  }
}

extern "C" void kernel_launch(void* const* d_in, const int* in_sizes, int n_in,
                              void* d_out, int out_size, void* d_ws, size_t ws_size,
                              hipStream_t stream) {
  const float* cost1 = (const float*)d_in[0];  // -> att_l2r (triu)
  const float* cost2 = (const float*)d_in[1];  // -> att_r2l (tril)
  float* out = (float*)d_out;                  // [4, H, W]
  float* w = (float*)d_ws;
  float* disp_r2l_ini = w;                     // 32768 floats (from cost2)
  float* disp_l2r_ini = w + 32768;             // (from cost1)
  float* cs_l2r       = w + 65536;             // colsums of att_l2r -> vm_left
  float* cs_r2l       = w + 98304;             // colsums of att_r2l -> vm_right

  hipMemsetAsync(cs_l2r, 0, 2 * (size_t)H * W * sizeof(float), stream);

  attn_stats_all<<<2 * H * SPLIT, 512, 0, stream>>>(
      cost1, cost2, disp_r2l_ini, disp_l2r_ini, cs_r2l, cs_l2r, out);

  // ch0 = regress(att_r2l, vm_left); ch1 = regress(att_l2r, vm_right)
  fill_rows<<<2 * H, 64, 0, stream>>>(disp_r2l_ini, cs_l2r,
                                      disp_l2r_ini, cs_r2l, out);
}

// Round 4
// 213.747 us; speedup vs baseline: 1.1011x; 1.1011x over previous
//
#include <hip/hip_runtime.h>
#include <float.h>

#define H 64
#define W 512

// ---------------------------------------------------------------------------
// Fused masked-exp-norm row statistics, triangular-work-only.
// Each wave owns row index i for BOTH tensors: tril(cost2) row i has i+1
// valid elements, triu(cost1) row i has 512-i -> combined 513 = perfectly
// balanced. Rows are processed in 64-element chunks j = c*64+lane with
// statically-unrolled chunk loops guarded by wave-uniform `c<=ci` / `c>=ci`
// (so cacc[] keeps static register indexing; masked chunks cost ~0).
// Boundary-chunk masked lanes are set to -FLT_MAX so exp()->0 removes all
// per-element validity selects from the hot phase-2 loop.
// Per row: disp_ini = i - sum(att*j); colsum[j] += att; raw = 3-tap subpixel
// around argmax, using  sum(e*pr over taps) = pscale*(i*t0 - w0)  (tril)
//                                           = pscale*(w0 - i*t0)  (triu),
// with t0 = sum(e) and w0 = sum(e*j) over taps hi-1..hi+1 (out-of-triangle
// taps have e=0, matching the reference's zero-padded gather).
// VGPR budget: val[8]+cacc_t[8]+cacc_u[8]=24 arrays; __launch_bounds__(256,8)
// pins us under the 64-VGPR occupancy cliff (R3 lesson).
// ---------------------------------------------------------------------------
__global__ __launch_bounds__(256, 8) void attn_stats_all(
    const float* __restrict__ cost1, const float* __restrict__ cost2,
    float* __restrict__ disp_r2l, float* __restrict__ disp_l2r,
    float* __restrict__ cs_r2l,  float* __restrict__ cs_l2r,
    float* __restrict__ out)
{
  __shared__ float scol[2][W];          // [0]=tril(att_r2l), [1]=triu(att_l2r)
  const int tid  = threadIdx.x;
  const int lane = tid & 63;
  const int wid  = tid >> 6;            // 0..3
  const int b    = blockIdx.x;
  const int h    = b >> 5;
  const int slice = b & 31;             // 16 rows per block

  scol[0][tid] = 0.f; scol[0][256 + tid] = 0.f;
  scol[1][tid] = 0.f; scol[1][256 + tid] = 0.f;
  __syncthreads();

  float cacc_t[8], cacc_u[8];
  #pragma unroll
  for (int c = 0; c < 8; c++) { cacc_t[c] = 0.f; cacc_u[c] = 0.f; }

  const float pscale = 2.0f / 511.0f;   // linspace(0,2,512) step
  const float* baset = cost2 + (size_t)h * W * W;   // tril -> att_r2l
  const float* baseu = cost1 + (size_t)h * W * W;   // triu -> att_l2r
  float* rawt = out + 2 * H * W;        // gen_raw_disp(att_r2l, pos)
  float* rawu = out + 3 * H * W;        // gen_raw_disp(att_l2r, pos^T)

  for (int r = 0; r < 4; r++) {
    const int i  = slice * 16 + r * 4 + wid;
    const int ci = i >> 6;              // boundary chunk index
    const int ib = i & 63;
    const float fi = (float)i;

    // ================= TRIL (cost2): valid j <= i =================
    {
      const float* rp = baset + (size_t)i * W;
      float val[8];
      float best = -FLT_MAX; int bj = 1024;
      #pragma unroll
      for (int c = 0; c < 8; c++) {
        if (c <= ci) {
          float v = rp[c * 64 + lane];
          if (c == ci && lane > ib) v = -FLT_MAX;
          val[c] = v;
          if (v > best) { best = v; bj = c * 64 + lane; }   // first occurrence
        }
      }
      #pragma unroll
      for (int off = 32; off; off >>= 1) {
        const float ov = __shfl_xor(best, off);
        const int   oj = __shfl_xor(bj, off);
        if (ov > best || (ov == best && oj < bj)) { best = ov; bj = oj; }
      }
      const int hi = bj;                               // wave-uniform argmax
      const float mx = (i < W - 1) ? fmaxf(best, 0.f) : best;  // masked zeros join max
      float ssum = 0.f, wsum = 0.f, t0 = 0.f, w0 = 0.f;
      #pragma unroll
      for (int c = 0; c < 8; c++) {
        if (c <= ci) {
          const float e = __expf(val[c] - mx);         // masked lanes: exp(-inf)=0
          val[c] = e;
          const int j = c * 64 + lane;
          const float p = e * (float)j;
          ssum += e; wsum += p;
          if ((unsigned)(j - (hi - 1)) <= 2u) { t0 += e; w0 += p; }
        }
      }
      #pragma unroll
      for (int off = 32; off; off >>= 1) {
        ssum += __shfl_xor(ssum, off);
        wsum += __shfl_xor(wsum, off);
        t0   += __shfl_xor(t0, off);
        w0   += __shfl_xor(w0, off);
      }
      const float inv = 1.f / (ssum + 1e-8f);
      #pragma unroll
      for (int c = 0; c < 8; c++)
        if (c <= ci) cacc_t[c] += val[c] * inv;
      if (lane == 0) {
        disp_r2l[h * W + i] = fi - wsum * inv;
        const float n0 = t0 * inv;                     // sum of the 3 att taps
        const float t1 = pscale * (fi * t0 - w0);      // sum e*pr over taps
        rawt[h * W + i] = (t1 * inv) / (n0 < 0.1f ? 1.f : n0);
      }
    }

    // ================= TRIU (cost1): valid j >= i =================
    {
      const float* rp = baseu + (size_t)i * W;
      float val[8];
      float best = -FLT_MAX; int bj = 1024;
      #pragma unroll
      for (int c = 0; c < 8; c++) {
        if (c >= ci) {
          float v = rp[c * 64 + lane];
          if (c == ci && lane < ib) v = -FLT_MAX;
          val[c] = v;
          if (v > best) { best = v; bj = c * 64 + lane; }
        }
      }
      #pragma unroll
      for (int off = 32; off; off >>= 1) {
        const float ov = __shfl_xor(best, off);
        const int   oj = __shfl_xor(bj, off);
        if (ov > best || (ov == best && oj < bj)) { best = ov; bj = oj; }
      }
      const int hi = bj;
      const float mx = (i > 0) ? fmaxf(best, 0.f) : best;
      float ssum = 0.f, wsum = 0.f, t0 = 0.f, w0 = 0.f;
      #pragma unroll
      for (int c = 0; c < 8; c++) {
        if (c >= ci) {
          const float e = __expf(val[c] - mx);
          val[c] = e;
          const int j = c * 64 + lane;
          const float p = e * (float)j;
          ssum += e; wsum += p;
          if ((unsigned)(j - (hi - 1)) <= 2u) { t0 += e; w0 += p; }
        }
      }
      #pragma unroll
      for (int off = 32; off; off >>= 1) {
        ssum += __shfl_xor(ssum, off);
        wsum += __shfl_xor(wsum, off);
        t0   += __shfl_xor(t0, off);
        w0   += __shfl_xor(w0, off);
      }
      const float inv = 1.f / (ssum + 1e-8f);
      #pragma unroll
      for (int c = 0; c < 8; c++)
        if (c >= ci) cacc_u[c] += val[c] * inv;
      if (lane == 0) {
        disp_l2r[h * W + i] = fi - wsum * inv;
        const float n0 = t0 * inv;
        const float t1 = pscale * (w0 - fi * t0);
        rawu[h * W + i] = (t1 * inv) / (n0 < 0.1f ? 1.f : n0);
      }
    }
  }

  // colsum: regs -> LDS atomics (4-way cross-wave) -> global atomics
  #pragma unroll
  for (int c = 0; c < 8; c++) {
    atomicAdd(&scol[0][c * 64 + lane], cacc_t[c]);
    atomicAdd(&scol[1][c * 64 + lane], cacc_u[c]);
  }
  __syncthreads();
  #pragma unroll
  for (int q = 0; q < 2; q++) {
    const int col = q * 256 + tid;
    atomicAdd(&cs_r2l[h * W + col], scol[0][col]);
    atomicAdd(&cs_l2r[h * W + col], scol[1][col]);
  }
}

// ---------------------------------------------------------------------------
// Closed-form hole fill (the W-step scan converges to this):
//   valid i            -> disp_ini[i]
//   invalid, valid p<i -> disp_ini[p] * (1+1e-4)^-(i-p)   (left-to-right pass)
//   invalid prefix     -> disp_ini[p0] * (1+1e-4)^-(p0-i) (right-to-left pass)
//   no valid in row    -> 0
// One wave per (pair, h) row.
// ---------------------------------------------------------------------------
__global__ __launch_bounds__(64) void fill_rows(
    const float* __restrict__ dispA, const float* __restrict__ csA,
    const float* __restrict__ dispB, const float* __restrict__ csB,
    float* __restrict__ out)
{
  __shared__ float xrow[W];
  const int pair = blockIdx.x >> 6;   // 0: ch0 (r2l disp, vm_left), 1: ch1
  const int h    = blockIdx.x & 63;
  const float* dsp = (pair ? dispB : dispA) + h * W;
  const float* cs  = (pair ? csB  : csA ) + h * W;
  float* o = out + pair * (H * W) + h * W;
  const int lane = threadIdx.x;
  const int j0 = lane * 8;

  float x[8];
  bool m[8];
  int incl[8];
  int run = -1, fv = W;
  #pragma unroll
  for (int k = 0; k < 8; k++) {
    x[k] = dsp[j0 + k];
    m[k] = cs[j0 + k] > 0.1f;
    xrow[j0 + k] = x[k];
    if (m[k]) { run = j0 + k; if (fv == W) fv = j0 + k; }
    incl[k] = run;
  }
  // inclusive max-scan across lanes of "last valid index in my segment"
  int v = run;
  #pragma unroll
  for (int off = 1; off < 64; off <<= 1) {
    const int tv = __shfl_up(v, off);
    if (lane >= off) v = max(v, tv);
  }
  int excl = __shfl_up(v, 1);
  if (lane == 0) excl = -1;
  // first valid index in the whole row
  int p0 = fv;
  #pragma unroll
  for (int off = 32; off; off >>= 1) p0 = min(p0, __shfl_xor(p0, off));
  __syncthreads();

  const float C2 = -1.4426229e-4f;  // -log2(1 + 1e-4)
  #pragma unroll
  for (int k = 0; k < 8; k++) {
    const int jj = j0 + k;
    float ov;
    if (m[k]) {
      ov = x[k];
    } else {
      const int p = max(excl, incl[k]);
      if (p >= 0)        ov = xrow[p]  * exp2f(C2 * (float)(jj - p));
      else if (p0 < W)   ov = xrow[p0] * exp2f(C2 * (float)(p0 - jj));
      else               ov = 0.f;
    }
    o[jj] = ov;
  }
}

extern "C" void kernel_launch(void* const* d_in, const int* in_sizes, int n_in,
                              void* d_out, int out_size, void* d_ws, size_t ws_size,
                              hipStream_t stream) {
  const float* cost1 = (const float*)d_in[0];  // -> att_l2r (triu)
  const float* cost2 = (const float*)d_in[1];  // -> att_r2l (tril)
  float* out = (float*)d_out;                  // [4, H, W]
  float* w = (float*)d_ws;
  float* disp_r2l_ini = w;                     // 32768 floats (from cost2)
  float* disp_l2r_ini = w + 32768;             // (from cost1)
  float* cs_l2r       = w + 65536;             // colsums of att_l2r -> vm_left
  float* cs_r2l       = w + 98304;             // colsums of att_r2l -> vm_right

  hipMemsetAsync(cs_l2r, 0, 2 * (size_t)H * W * sizeof(float), stream);

  attn_stats_all<<<2 * H * 16, 256, 0, stream>>>(
      cost1, cost2, disp_r2l_ini, disp_l2r_ini, cs_r2l, cs_l2r, out);

  // ch0 = regress(att_r2l, vm_left); ch1 = regress(att_l2r, vm_right)
  fill_rows<<<2 * H, 64, 0, stream>>>(disp_r2l_ini, cs_l2r,
                                      disp_l2r_ini, cs_r2l, out);
}